// Round 1
// baseline (194.968 us; speedup 1.0000x reference)
//
#include <hip/hip_runtime.h>
#include <math.h>

#define T_DIM 2048
#define B_DIM 64
#define H_DIM 1024

// ---------------------------------------------------------------------------
// K1: q[b,h] = sum_g hidden[b,g] * W[g,h]
// grid (H/256, B), block 256.
// NOTE: b_attn contributes a per-b constant to scores -> cancels in softmax.
// ---------------------------------------------------------------------------
__global__ void qproj_kernel(const float* __restrict__ hidden,
                             const float* __restrict__ W,
                             float* __restrict__ q) {
    const int b = blockIdx.y;
    const int h = blockIdx.x * 256 + threadIdx.x;

    __shared__ float hs[H_DIM];
    for (int i = threadIdx.x; i < H_DIM; i += 256)
        hs[i] = hidden[b * H_DIM + i];
    __syncthreads();

    float acc = 0.f;
#pragma unroll 8
    for (int g = 0; g < H_DIM; ++g) {
        // hs[g]: LDS broadcast (free). W read: coalesced across threads (h).
        acc += hs[g] * W[(size_t)g * H_DIM + h];
    }
    q[b * H_DIM + h] = acc;
}

// ---------------------------------------------------------------------------
// K2 (dominant): scores[b,t] = sum_h enc[t,b,h] * q[b,h]
// enc layout [T,B,H]: (t,b,h) at ((size_t)t*B_DIM + b)*H_DIM + h  (contiguous in h)
// grid (B, T/64), block 256 = 4 waves; each wave handles 16 t values.
// q fragment held in registers (4x float4 per lane) across the whole t-loop.
// ---------------------------------------------------------------------------
__global__ void scores_kernel(const float* __restrict__ enc,
                              const float* __restrict__ q,
                              float* __restrict__ scores) {
    const int b = blockIdx.x;
    const int wave = threadIdx.x >> 6;
    const int lane = threadIdx.x & 63;

    // Hoist this lane's q fragment into registers: q[b, (k*64+lane)*4 .. +3]
    const float4* qv = (const float4*)(q + (size_t)b * H_DIM);
    float4 qr0 = qv[0 * 64 + lane];
    float4 qr1 = qv[1 * 64 + lane];
    float4 qr2 = qv[2 * 64 + lane];
    float4 qr3 = qv[3 * 64 + lane];

    const int t0 = blockIdx.y * 64 + wave * 16;
#pragma unroll 2
    for (int i = 0; i < 16; ++i) {
        const int t = t0 + i;
        const float4* e = (const float4*)(enc + ((size_t)t * B_DIM + b) * H_DIM);
        float4 e0 = e[0 * 64 + lane];
        float4 e1 = e[1 * 64 + lane];
        float4 e2 = e[2 * 64 + lane];
        float4 e3 = e[3 * 64 + lane];

        float acc = e0.x * qr0.x + e0.y * qr0.y + e0.z * qr0.z + e0.w * qr0.w;
        acc += e1.x * qr1.x + e1.y * qr1.y + e1.z * qr1.z + e1.w * qr1.w;
        acc += e2.x * qr2.x + e2.y * qr2.y + e2.z * qr2.z + e2.w * qr2.w;
        acc += e3.x * qr3.x + e3.y * qr3.y + e3.z * qr3.z + e3.w * qr3.w;

        // wave (64-lane) reduction
#pragma unroll
        for (int off = 32; off > 0; off >>= 1)
            acc += __shfl_down(acc, off);
        if (lane == 0)
            scores[b * T_DIM + t] = acc;
    }
}

// ---------------------------------------------------------------------------
// K3: out[b,0,t] = softmax_t(scores[b,t]); one block per b, 256 threads,
// 8 t-values per thread.
// ---------------------------------------------------------------------------
__global__ void softmax_kernel(const float* __restrict__ scores,
                               float* __restrict__ out) {
    const int b = blockIdx.x;
    const int tid = threadIdx.x;
    const int wave = tid >> 6;
    const int lane = tid & 63;

    float v[8];
    float m = -INFINITY;
#pragma unroll
    for (int i = 0; i < 8; ++i) {
        v[i] = scores[b * T_DIM + tid + i * 256];
        m = fmaxf(m, v[i]);
    }
    // wave max (all lanes get it)
#pragma unroll
    for (int off = 1; off < 64; off <<= 1)
        m = fmaxf(m, __shfl_xor(m, off));

    __shared__ float red[4];
    if (lane == 0) red[wave] = m;
    __syncthreads();
    m = fmaxf(fmaxf(red[0], red[1]), fmaxf(red[2], red[3]));
    __syncthreads();

    float s = 0.f;
#pragma unroll
    for (int i = 0; i < 8; ++i) {
        v[i] = expf(v[i] - m);
        s += v[i];
    }
#pragma unroll
    for (int off = 1; off < 64; off <<= 1)
        s += __shfl_xor(s, off);
    if (lane == 0) red[wave] = s;
    __syncthreads();
    s = red[0] + red[1] + red[2] + red[3];

    const float inv = 1.0f / s;
#pragma unroll
    for (int i = 0; i < 8; ++i)
        out[b * T_DIM + tid + i * 256] = v[i] * inv;
}

extern "C" void kernel_launch(void* const* d_in, const int* in_sizes, int n_in,
                              void* d_out, int out_size, void* d_ws, size_t ws_size,
                              hipStream_t stream) {
    const float* hidden = (const float*)d_in[0];  // [1,B,H]
    const float* enc    = (const float*)d_in[1];  // [T,B,H]
    const float* W      = (const float*)d_in[2];  // [H,H]
    // d_in[3] = b_attn: per-b constant under softmax -> mathematically cancels.

    float* out = (float*)d_out;                   // [B,1,T]

    float* q      = (float*)d_ws;                       // B*H floats   (256 KB)
    float* scores = (float*)d_ws + (size_t)B_DIM * H_DIM; // B*T floats (512 KB)

    qproj_kernel<<<dim3(H_DIM / 256, B_DIM), 256, 0, stream>>>(hidden, W, q);
    scores_kernel<<<dim3(B_DIM, T_DIM / 64), 256, 0, stream>>>(enc, q, scores);
    softmax_kernel<<<dim3(B_DIM), 256, 0, stream>>>(scores, out);
}

// Round 3
// 188.733 us; speedup vs baseline: 1.0330x; 1.0330x over previous
//
#include <hip/hip_runtime.h>
#include <math.h>

#define T_DIM 2048
#define B_DIM 64
#define H_DIM 1024
#define TC 4  // t-values per block in scores kernel

typedef float f4 __attribute__((ext_vector_type(4)));  // native vec for nt-loads

// ---------------------------------------------------------------------------
// K1: q[b,h] = sum_g hidden[b,g] * W[g,h]
// grid (H/256, B), block 512 = 8 waves. Wave w sums g in [128w, 128w+128)
// with float4 W loads (1 KB/instr coalesced); LDS reduce across waves.
// b_attn is constant in t under softmax -> dropped exactly.
// ---------------------------------------------------------------------------
__global__ __launch_bounds__(512) void qproj_kernel(
    const float* __restrict__ hidden,
    const float* __restrict__ W,
    float* __restrict__ q) {
    const int b    = blockIdx.y;
    const int h0   = blockIdx.x * 256;
    const int wave = threadIdx.x >> 6;
    const int lane = threadIdx.x & 63;

    __shared__ float hs[H_DIM];
    __shared__ f4    part[8][64];

    for (int i = threadIdx.x; i < H_DIM; i += 512)
        hs[i] = hidden[b * H_DIM + i];
    __syncthreads();

    const int gbase = wave * 128;
    const f4* Wv = (const f4*)(W + (size_t)gbase * H_DIM + h0);
    f4 acc = {0.f, 0.f, 0.f, 0.f};
#pragma unroll 8
    for (int g = 0; g < 128; ++g) {
        const float hg = hs[gbase + g];
        const f4    wv = Wv[g * 256 + lane];  // W[gbase+g][h0 + lane*4 ..+3]
        acc += hg * wv;
    }
    part[wave][lane] = acc;
    __syncthreads();

    if (wave == 0) {
        f4 s = part[0][lane];
#pragma unroll
        for (int w = 1; w < 8; ++w) s += part[w][lane];
        ((f4*)(q + (size_t)b * H_DIM + h0))[lane] = s;
    }
}

// ---------------------------------------------------------------------------
// K2 (dominant, memory-bound): scores[b,t] = sum_h enc[t,b,h] * q[b,h]
// enc [T,B,H]: row r = t*64+b is 4 KB; 64 consecutive rows = all b of one t.
// Block: 512 threads (8 waves), grid (T/TC, 2). Wave w owns b = y*32+w*4 ..+3
// (same 4 b's for every t!) -> q fragments held in REGISTERS, loaded once.
// Per t, wave w reads a contiguous 16 KB slab; block sweep is fully
// sequential over enc. Nontemporal enc loads keep q resident in L2.
// ---------------------------------------------------------------------------
__global__ __launch_bounds__(512) void scores_kernel(
    const float* __restrict__ enc,
    const float* __restrict__ q,
    float* __restrict__ scores) {
    const int wave = threadIdx.x >> 6;
    const int lane = threadIdx.x & 63;
    const int t0   = blockIdx.x * TC;
    const int b0   = blockIdx.y * 32 + wave * 4;

    // q fragments for this wave's 4 b's: qf[i][k] = q[b0+i][k*256 + lane*4 ..+3]
    f4 qf[4][4];
#pragma unroll
    for (int i = 0; i < 4; ++i) {
        const f4* qv = (const f4*)(q + (size_t)(b0 + i) * H_DIM);
#pragma unroll
        for (int k = 0; k < 4; ++k) qf[i][k] = qv[k * 64 + lane];
    }

    for (int tt = 0; tt < TC; ++tt) {
        const int t = t0 + tt;
        const f4* base = (const f4*)(enc + ((size_t)t * B_DIM + b0) * H_DIM);
#pragma unroll 2
        for (int i = 0; i < 4; ++i) {
            const f4* e = base + i * 256;
            const f4 e0 = __builtin_nontemporal_load(&e[0 * 64 + lane]);
            const f4 e1 = __builtin_nontemporal_load(&e[1 * 64 + lane]);
            const f4 e2 = __builtin_nontemporal_load(&e[2 * 64 + lane]);
            const f4 e3 = __builtin_nontemporal_load(&e[3 * 64 + lane]);

            float acc = e0.x * qf[i][0].x + e0.y * qf[i][0].y +
                        e0.z * qf[i][0].z + e0.w * qf[i][0].w;
            acc += e1.x * qf[i][1].x + e1.y * qf[i][1].y +
                   e1.z * qf[i][1].z + e1.w * qf[i][1].w;
            acc += e2.x * qf[i][2].x + e2.y * qf[i][2].y +
                   e2.z * qf[i][2].z + e2.w * qf[i][2].w;
            acc += e3.x * qf[i][3].x + e3.y * qf[i][3].y +
                   e3.z * qf[i][3].z + e3.w * qf[i][3].w;

#pragma unroll
            for (int off = 32; off > 0; off >>= 1)
                acc += __shfl_down(acc, off);
            if (lane == 0)
                scores[(size_t)(b0 + i) * T_DIM + t] = acc;
        }
    }
}

// ---------------------------------------------------------------------------
// K3: out[b,0,t] = softmax_t(scores[b,t]); one block (512 thr) per b,
// one float4 per thread.
// ---------------------------------------------------------------------------
__global__ __launch_bounds__(512) void softmax_kernel(
    const float* __restrict__ scores,
    float* __restrict__ out) {
    const int b    = blockIdx.x;
    const int tid  = threadIdx.x;
    const int wave = tid >> 6;
    const int lane = tid & 63;

    f4 v = ((const f4*)(scores + (size_t)b * T_DIM))[tid];

    float m = fmaxf(fmaxf(v.x, v.y), fmaxf(v.z, v.w));
#pragma unroll
    for (int off = 1; off < 64; off <<= 1)
        m = fmaxf(m, __shfl_xor(m, off));

    __shared__ float redm[8], reds[8];
    if (lane == 0) redm[wave] = m;
    __syncthreads();
    m = redm[0];
#pragma unroll
    for (int w = 1; w < 8; ++w) m = fmaxf(m, redm[w]);

    v.x = expf(v.x - m); v.y = expf(v.y - m);
    v.z = expf(v.z - m); v.w = expf(v.w - m);
    float s = v.x + v.y + v.z + v.w;
#pragma unroll
    for (int off = 1; off < 64; off <<= 1)
        s += __shfl_xor(s, off);
    if (lane == 0) reds[wave] = s;
    __syncthreads();
    s = reds[0];
#pragma unroll
    for (int w = 1; w < 8; ++w) s += reds[w];

    const float inv = 1.0f / s;
    v *= inv;
    ((f4*)(out + (size_t)b * T_DIM))[tid] = v;
}

extern "C" void kernel_launch(void* const* d_in, const int* in_sizes, int n_in,
                              void* d_out, int out_size, void* d_ws, size_t ws_size,
                              hipStream_t stream) {
    const float* hidden = (const float*)d_in[0];  // [1,B,H]
    const float* enc    = (const float*)d_in[1];  // [T,B,H]
    const float* W      = (const float*)d_in[2];  // [H,H]
    // d_in[3] = b_attn: adds a per-b constant to scores -> cancels in softmax.

    float* out    = (float*)d_out;                        // [B,1,T]
    float* q      = (float*)d_ws;                         // B*H  (256 KB)
    float* scores = (float*)d_ws + (size_t)B_DIM * H_DIM; // B*T  (512 KB)

    qproj_kernel <<<dim3(H_DIM / 256, B_DIM), 512, 0, stream>>>(hidden, W, q);
    scores_kernel<<<dim3(T_DIM / TC, 2),      512, 0, stream>>>(enc, q, scores);
    softmax_kernel<<<dim3(B_DIM),             512, 0, stream>>>(scores, out);
}

// Round 4
// 119.585 us; speedup vs baseline: 1.6304x; 1.5782x over previous
//
#include <hip/hip_runtime.h>
#include <math.h>

#define T_DIM 2048
#define B_DIM 64
#define H_DIM 1024
#define TC 4  // t-values per block in scores kernel

typedef float f4 __attribute__((ext_vector_type(4)));

// ---------------------------------------------------------------------------
// K1: q[b,h] = sum_g hidden[b,g] * W[g,h]
// grid (H/256, B), block 512 = 8 waves. Wave w sums g in [128w, 128w+128)
// with float4 W loads; LDS reduce across waves.
// b_attn is constant in t under softmax -> dropped exactly.
// ---------------------------------------------------------------------------
__global__ __launch_bounds__(512) void qproj_kernel(
    const float* __restrict__ hidden,
    const float* __restrict__ W,
    float* __restrict__ q) {
    const int b    = blockIdx.y;
    const int h0   = blockIdx.x * 256;
    const int wave = threadIdx.x >> 6;
    const int lane = threadIdx.x & 63;

    __shared__ float hs[H_DIM];
    __shared__ f4    part[8][64];

    for (int i = threadIdx.x; i < H_DIM; i += 512)
        hs[i] = hidden[b * H_DIM + i];
    __syncthreads();

    const int gbase = wave * 128;
    const f4* Wv = (const f4*)(W + (size_t)gbase * H_DIM + h0);
    f4 acc = {0.f, 0.f, 0.f, 0.f};
#pragma unroll 8
    for (int g = 0; g < 128; ++g) {
        const float hg = hs[gbase + g];
        const f4    wv = Wv[g * 256 + lane];
        acc += hg * wv;
    }
    part[wave][lane] = acc;
    __syncthreads();

    if (wave == 0) {
        f4 s = part[0][lane];
#pragma unroll
        for (int w = 1; w < 8; ++w) s += part[w][lane];
        ((f4*)(q + (size_t)b * H_DIM + h0))[lane] = s;
    }
}

// ---------------------------------------------------------------------------
// K2 (dominant): scores_t[t][b] = sum_h enc[t,b,h] * q[b,h]
// 2 rows (b, b+1) per wave -> qf only 32 VGPR, 8 loads in flight, high occ.
// Batched parity butterfly: 6 shuffles reduce BOTH rows at once.
// grid (T/TC, B/16) = (512, 4) = 2048 blocks, 512 thr (8 waves).
// Wave w owns b0 = y*16 + 2w (same b's for every t -> q stays in registers).
// ---------------------------------------------------------------------------
__global__ __launch_bounds__(512) void scores_kernel(
    const float* __restrict__ enc,
    const float* __restrict__ q,
    float* __restrict__ scores_t) {
    const int wave = threadIdx.x >> 6;
    const int lane = threadIdx.x & 63;
    const int t0   = blockIdx.x * TC;
    const int b0   = blockIdx.y * 16 + wave * 2;

    f4 qf0[4], qf1[4];
    {
        const f4* qv0 = (const f4*)(q + (size_t)b0 * H_DIM);
        const f4* qv1 = (const f4*)(q + (size_t)(b0 + 1) * H_DIM);
#pragma unroll
        for (int k = 0; k < 4; ++k) {
            qf0[k] = qv0[k * 64 + lane];
            qf1[k] = qv1[k * 64 + lane];
        }
    }

#pragma unroll
    for (int tt = 0; tt < TC; ++tt) {
        const int t = t0 + tt;
        const f4* e0p = (const f4*)(enc + ((size_t)t * B_DIM + b0) * H_DIM);
        const f4* e1p = e0p + 256;  // row b0+1 (contiguous 4 KB later)

        f4 E0[4], E1[4];
#pragma unroll
        for (int k = 0; k < 4; ++k) E0[k] = e0p[k * 64 + lane];
#pragma unroll
        for (int k = 0; k < 4; ++k) E1[k] = e1p[k * 64 + lane];

        float a0 = 0.f, a1 = 0.f;
#pragma unroll
        for (int k = 0; k < 4; ++k) {
            a0 += E0[k].x * qf0[k].x + E0[k].y * qf0[k].y +
                  E0[k].z * qf0[k].z + E0[k].w * qf0[k].w;
            a1 += E1[k].x * qf1[k].x + E1[k].y * qf1[k].y +
                  E1[k].z * qf1[k].z + E1[k].w * qf1[k].w;
        }

        // Parity butterfly: even lanes end with full a0-sum, odd with a1-sum.
        const bool odd = lane & 1;
        float m = odd ? a1 : a0;
        float o = odd ? a0 : a1;
        m += __shfl_xor(o, 1);
#pragma unroll
        for (int off = 2; off < 64; off <<= 1)
            m += __shfl_xor(m, off);

        if (lane < 2)
            scores_t[(size_t)t * B_DIM + b0 + lane] = m;  // 2 adjacent dwords
    }
}

// ---------------------------------------------------------------------------
// K3: out[b,0,t] = softmax_t(scores_t[t][b]); block per b, 512 thr.
// Strided scores read is L2-resident (512 KB written just before).
// ---------------------------------------------------------------------------
__global__ __launch_bounds__(512) void softmax_kernel(
    const float* __restrict__ scores_t,
    float* __restrict__ out) {
    const int b    = blockIdx.x;
    const int tid  = threadIdx.x;
    const int wave = tid >> 6;
    const int lane = tid & 63;

    float v[4];
#pragma unroll
    for (int j = 0; j < 4; ++j)
        v[j] = scores_t[(size_t)(tid * 4 + j) * B_DIM + b];

    float m = fmaxf(fmaxf(v[0], v[1]), fmaxf(v[2], v[3]));
#pragma unroll
    for (int off = 1; off < 64; off <<= 1)
        m = fmaxf(m, __shfl_xor(m, off));

    __shared__ float redm[8], reds[8];
    if (lane == 0) redm[wave] = m;
    __syncthreads();
    m = redm[0];
#pragma unroll
    for (int w = 1; w < 8; ++w) m = fmaxf(m, redm[w]);

    float s = 0.f;
#pragma unroll
    for (int j = 0; j < 4; ++j) {
        v[j] = expf(v[j] - m);
        s += v[j];
    }
#pragma unroll
    for (int off = 1; off < 64; off <<= 1)
        s += __shfl_xor(s, off);
    if (lane == 0) reds[wave] = s;
    __syncthreads();
    s = reds[0];
#pragma unroll
    for (int w = 1; w < 8; ++w) s += reds[w];

    const float inv = 1.0f / s;
    f4 ov = {v[0] * inv, v[1] * inv, v[2] * inv, v[3] * inv};
    ((f4*)(out + (size_t)b * T_DIM))[tid] = ov;
}

extern "C" void kernel_launch(void* const* d_in, const int* in_sizes, int n_in,
                              void* d_out, int out_size, void* d_ws, size_t ws_size,
                              hipStream_t stream) {
    const float* hidden = (const float*)d_in[0];  // [1,B,H]
    const float* enc    = (const float*)d_in[1];  // [T,B,H]
    const float* W      = (const float*)d_in[2];  // [H,H]
    // d_in[3] = b_attn: per-b constant under softmax -> cancels exactly.

    float* out      = (float*)d_out;                        // [B,1,T]
    float* q        = (float*)d_ws;                         // B*H  (256 KB)
    float* scores_t = (float*)d_ws + (size_t)B_DIM * H_DIM; // T*B  (512 KB)

    qproj_kernel  <<<dim3(H_DIM / 256, B_DIM),       512, 0, stream>>>(hidden, W, q);
    scores_kernel <<<dim3(T_DIM / TC, B_DIM / 16),   512, 0, stream>>>(enc, q, scores_t);
    softmax_kernel<<<dim3(B_DIM),                    512, 0, stream>>>(scores_t, out);
}

// Round 5
// 100.521 us; speedup vs baseline: 1.9396x; 1.1897x over previous
//
#include <hip/hip_runtime.h>
#include <math.h>

#define T_DIM 2048
#define B_DIM 64
#define H_DIM 1024
#define TC 8  // t-values per block in scores kernel

typedef float f4 __attribute__((ext_vector_type(4)));

// ---------------------------------------------------------------------------
// K1: q[b,h] = sum_g hidden[b,g] * W[g,h]
// grid (4, 16), block 512 = 8 waves. Block handles 4 b-rows x 256 h-cols.
// Wave w sums g in [128w, 128w+128): per g ONE W load feeds 4 b-accumulators
// (W L2 traffic /4 vs one-b-per-block). LDS reduce across waves at the end.
// b_attn is constant in t under softmax -> dropped exactly.
// ---------------------------------------------------------------------------
__global__ __launch_bounds__(512) void qproj_kernel(
    const float* __restrict__ hidden,
    const float* __restrict__ W,
    float* __restrict__ q) {
    const int b0   = blockIdx.y * 4;
    const int h0   = blockIdx.x * 256;
    const int wave = threadIdx.x >> 6;
    const int lane = threadIdx.x & 63;

    __shared__ float hs[4][H_DIM];
    __shared__ f4    part[8][4][64];

    for (int i = threadIdx.x; i < 4 * H_DIM; i += 512)
        hs[i >> 10][i & 1023] = hidden[(size_t)b0 * H_DIM + i];
    __syncthreads();

    const int gbase = wave * 128;
    const f4* Wv = (const f4*)(W + (size_t)gbase * H_DIM + h0);
    f4 acc0 = {0,0,0,0}, acc1 = {0,0,0,0}, acc2 = {0,0,0,0}, acc3 = {0,0,0,0};
#pragma unroll 4
    for (int g = 0; g < 128; ++g) {
        const f4 wv = Wv[g * 256 + lane];
        acc0 += hs[0][gbase + g] * wv;
        acc1 += hs[1][gbase + g] * wv;
        acc2 += hs[2][gbase + g] * wv;
        acc3 += hs[3][gbase + g] * wv;
    }
    part[wave][0][lane] = acc0;
    part[wave][1][lane] = acc1;
    part[wave][2][lane] = acc2;
    part[wave][3][lane] = acc3;
    __syncthreads();

    if (wave < 4) {  // wave w reduces b-row w
        f4 s = part[0][wave][lane];
#pragma unroll
        for (int w = 1; w < 8; ++w) s += part[w][wave][lane];
        ((f4*)(q + (size_t)(b0 + wave) * H_DIM + h0))[lane] = s;
    }
}

// ---------------------------------------------------------------------------
// K2 (dominant): scores_t[t][b] = sum_h enc[t,b,h] * q[b,h]
// 2 rows (b, b+1) per wave -> qf 32 VGPR, high occupancy.
// Batched parity butterfly: 6 shuffles reduce BOTH rows at once.
// grid (T/TC, B/16) = (256, 4) = 1024 blocks, 512 thr (8 waves).
// Wave w owns b0 = y*16 + 2w (same b's for every t -> q stays in registers).
// enc loads nontemporal: read-once stream, keep q/scores resident in L2.
// ---------------------------------------------------------------------------
__global__ __launch_bounds__(512) void scores_kernel(
    const float* __restrict__ enc,
    const float* __restrict__ q,
    float* __restrict__ scores_t) {
    const int wave = threadIdx.x >> 6;
    const int lane = threadIdx.x & 63;
    const int t0   = blockIdx.x * TC;
    const int b0   = blockIdx.y * 16 + wave * 2;

    f4 qf0[4], qf1[4];
    {
        const f4* qv0 = (const f4*)(q + (size_t)b0 * H_DIM);
        const f4* qv1 = (const f4*)(q + (size_t)(b0 + 1) * H_DIM);
#pragma unroll
        for (int k = 0; k < 4; ++k) {
            qf0[k] = qv0[k * 64 + lane];
            qf1[k] = qv1[k * 64 + lane];
        }
    }

#pragma unroll 2
    for (int tt = 0; tt < TC; ++tt) {
        const int t = t0 + tt;
        const f4* e0p = (const f4*)(enc + ((size_t)t * B_DIM + b0) * H_DIM);
        const f4* e1p = e0p + 256;  // row b0+1

        f4 E0[4], E1[4];
#pragma unroll
        for (int k = 0; k < 4; ++k)
            E0[k] = __builtin_nontemporal_load(&e0p[k * 64 + lane]);
#pragma unroll
        for (int k = 0; k < 4; ++k)
            E1[k] = __builtin_nontemporal_load(&e1p[k * 64 + lane]);

        float a0 = 0.f, a1 = 0.f;
#pragma unroll
        for (int k = 0; k < 4; ++k) {
            a0 += E0[k].x * qf0[k].x + E0[k].y * qf0[k].y +
                  E0[k].z * qf0[k].z + E0[k].w * qf0[k].w;
            a1 += E1[k].x * qf1[k].x + E1[k].y * qf1[k].y +
                  E1[k].z * qf1[k].z + E1[k].w * qf1[k].w;
        }

        // Parity butterfly: lane parity selects which row's sum it carries.
        const bool odd = lane & 1;
        float m = odd ? a1 : a0;
        float o = odd ? a0 : a1;
        m += __shfl_xor(o, 1);
#pragma unroll
        for (int off = 2; off < 64; off <<= 1)
            m += __shfl_xor(m, off);

        if (lane < 2)
            scores_t[(size_t)t * B_DIM + b0 + lane] = m;  // 2 adjacent dwords
    }
}

// ---------------------------------------------------------------------------
// K3: out[b,0,t] = softmax_t(scores_t[t][b]); block per b, 512 thr.
// ---------------------------------------------------------------------------
__global__ __launch_bounds__(512) void softmax_kernel(
    const float* __restrict__ scores_t,
    float* __restrict__ out) {
    const int b    = blockIdx.x;
    const int tid  = threadIdx.x;
    const int wave = tid >> 6;
    const int lane = tid & 63;

    float v[4];
#pragma unroll
    for (int j = 0; j < 4; ++j)
        v[j] = scores_t[(size_t)(tid * 4 + j) * B_DIM + b];

    float m = fmaxf(fmaxf(v[0], v[1]), fmaxf(v[2], v[3]));
#pragma unroll
    for (int off = 1; off < 64; off <<= 1)
        m = fmaxf(m, __shfl_xor(m, off));

    __shared__ float redm[8], reds[8];
    if (lane == 0) redm[wave] = m;
    __syncthreads();
    m = redm[0];
#pragma unroll
    for (int w = 1; w < 8; ++w) m = fmaxf(m, redm[w]);

    float s = 0.f;
#pragma unroll
    for (int j = 0; j < 4; ++j) {
        v[j] = expf(v[j] - m);
        s += v[j];
    }
#pragma unroll
    for (int off = 1; off < 64; off <<= 1)
        s += __shfl_xor(s, off);
    if (lane == 0) reds[wave] = s;
    __syncthreads();
    s = reds[0];
#pragma unroll
    for (int w = 1; w < 8; ++w) s += reds[w];

    const float inv = 1.0f / s;
    f4 ov = {v[0] * inv, v[1] * inv, v[2] * inv, v[3] * inv};
    ((f4*)(out + (size_t)b * T_DIM))[tid] = ov;
}

extern "C" void kernel_launch(void* const* d_in, const int* in_sizes, int n_in,
                              void* d_out, int out_size, void* d_ws, size_t ws_size,
                              hipStream_t stream) {
    const float* hidden = (const float*)d_in[0];  // [1,B,H]
    const float* enc    = (const float*)d_in[1];  // [T,B,H]
    const float* W      = (const float*)d_in[2];  // [H,H]
    // d_in[3] = b_attn: per-b constant under softmax -> cancels exactly.

    float* out      = (float*)d_out;                        // [B,1,T]
    float* q        = (float*)d_ws;                         // B*H  (256 KB)
    float* scores_t = (float*)d_ws + (size_t)B_DIM * H_DIM; // T*B  (512 KB)

    qproj_kernel  <<<dim3(H_DIM / 256, B_DIM / 4), 512, 0, stream>>>(hidden, W, q);
    scores_kernel <<<dim3(T_DIM / TC, B_DIM / 16), 512, 0, stream>>>(enc, q, scores_t);
    softmax_kernel<<<dim3(B_DIM),                  512, 0, stream>>>(scores_t, out);
}

// Round 6
// 98.567 us; speedup vs baseline: 1.9780x; 1.0198x over previous
//
#include <hip/hip_runtime.h>
#include <math.h>

#define T_DIM 2048
#define B_DIM 64
#define H_DIM 1024
#define TC 16  // t-values per block in scores kernel

typedef float f4 __attribute__((ext_vector_type(4)));

// ---------------------------------------------------------------------------
// K1: q[b,h] = sum_g hidden[b,g] * W[g,h]
// grid (4, 16), block 512 = 8 waves. Block: 4 b-rows x 256 h-cols; one W load
// feeds 4 b-accumulators. LDS reduce across waves.
// b_attn is constant in t under softmax -> dropped exactly.
// ---------------------------------------------------------------------------
__global__ __launch_bounds__(512) void qproj_kernel(
    const float* __restrict__ hidden,
    const float* __restrict__ W,
    float* __restrict__ q) {
    const int b0   = blockIdx.y * 4;
    const int h0   = blockIdx.x * 256;
    const int wave = threadIdx.x >> 6;
    const int lane = threadIdx.x & 63;

    __shared__ float hs[4][H_DIM];
    __shared__ f4    part[8][4][64];

    for (int i = threadIdx.x; i < 4 * H_DIM; i += 512)
        hs[i >> 10][i & 1023] = hidden[(size_t)b0 * H_DIM + i];
    __syncthreads();

    const int gbase = wave * 128;
    const f4* Wv = (const f4*)(W + (size_t)gbase * H_DIM + h0);
    f4 acc0 = {0,0,0,0}, acc1 = {0,0,0,0}, acc2 = {0,0,0,0}, acc3 = {0,0,0,0};
#pragma unroll 4
    for (int g = 0; g < 128; ++g) {
        const f4 wv = Wv[g * 256 + lane];
        acc0 += hs[0][gbase + g] * wv;
        acc1 += hs[1][gbase + g] * wv;
        acc2 += hs[2][gbase + g] * wv;
        acc3 += hs[3][gbase + g] * wv;
    }
    part[wave][0][lane] = acc0;
    part[wave][1][lane] = acc1;
    part[wave][2][lane] = acc2;
    part[wave][3][lane] = acc3;
    __syncthreads();

    if (wave < 4) {  // wave w reduces b-row w
        f4 s = part[0][wave][lane];
#pragma unroll
        for (int w = 1; w < 8; ++w) s += part[w][wave][lane];
        ((f4*)(q + (size_t)(b0 + wave) * H_DIM + h0))[lane] = s;
    }
}

// ---------------------------------------------------------------------------
// K2 (dominant): scores[b][t] = sum_h enc[t,b,h] * q[b,h]
// 2 rows (b, b+1) per wave -> qf 32 VGPR, high occupancy.
// Batched parity butterfly: 6 shuffles reduce BOTH rows at once.
// grid (T/TC, B/16) = (128, 4) = 512 blocks (2/CU), 512 thr (8 waves).
// Wave w owns b0 = y*16 + 2w (same b's for every t -> q stays in registers).
// enc loads nontemporal (read-once stream). Stores go to [B][T] layout so
// K3 reads coalesced; the 2 scattered dwords/t are absorbed by L2.
// ---------------------------------------------------------------------------
__global__ __launch_bounds__(512) void scores_kernel(
    const float* __restrict__ enc,
    const float* __restrict__ q,
    float* __restrict__ scores) {
    const int wave = threadIdx.x >> 6;
    const int lane = threadIdx.x & 63;
    const int t0   = blockIdx.x * TC;
    const int b0   = blockIdx.y * 16 + wave * 2;

    f4 qf0[4], qf1[4];
    {
        const f4* qv0 = (const f4*)(q + (size_t)b0 * H_DIM);
        const f4* qv1 = (const f4*)(q + (size_t)(b0 + 1) * H_DIM);
#pragma unroll
        for (int k = 0; k < 4; ++k) {
            qf0[k] = qv0[k * 64 + lane];
            qf1[k] = qv1[k * 64 + lane];
        }
    }

#pragma unroll 2
    for (int tt = 0; tt < TC; ++tt) {
        const int t = t0 + tt;
        const f4* e0p = (const f4*)(enc + ((size_t)t * B_DIM + b0) * H_DIM);
        const f4* e1p = e0p + 256;  // row b0+1

        f4 E0[4], E1[4];
#pragma unroll
        for (int k = 0; k < 4; ++k)
            E0[k] = __builtin_nontemporal_load(&e0p[k * 64 + lane]);
#pragma unroll
        for (int k = 0; k < 4; ++k)
            E1[k] = __builtin_nontemporal_load(&e1p[k * 64 + lane]);

        float a0 = 0.f, a1 = 0.f;
#pragma unroll
        for (int k = 0; k < 4; ++k) {
            a0 += E0[k].x * qf0[k].x + E0[k].y * qf0[k].y +
                  E0[k].z * qf0[k].z + E0[k].w * qf0[k].w;
            a1 += E1[k].x * qf1[k].x + E1[k].y * qf1[k].y +
                  E1[k].z * qf1[k].z + E1[k].w * qf1[k].w;
        }

        // Parity butterfly: lane parity selects which row's sum it carries.
        const bool odd = lane & 1;
        float m = odd ? a1 : a0;
        float o = odd ? a0 : a1;
        m += __shfl_xor(o, 1);
#pragma unroll
        for (int off = 2; off < 64; off <<= 1)
            m += __shfl_xor(m, off);

        if (lane < 2)
            scores[(size_t)(b0 + lane) * T_DIM + t] = m;
    }
}

// ---------------------------------------------------------------------------
// K3: out[b,0,t] = softmax_t(scores[b][t]); block per b, 512 thr,
// one f4 per thread — fully coalesced.
// ---------------------------------------------------------------------------
__global__ __launch_bounds__(512) void softmax_kernel(
    const float* __restrict__ scores,
    float* __restrict__ out) {
    const int b    = blockIdx.x;
    const int tid  = threadIdx.x;
    const int wave = tid >> 6;
    const int lane = tid & 63;

    f4 v = ((const f4*)(scores + (size_t)b * T_DIM))[tid];

    float m = fmaxf(fmaxf(v.x, v.y), fmaxf(v.z, v.w));
#pragma unroll
    for (int off = 1; off < 64; off <<= 1)
        m = fmaxf(m, __shfl_xor(m, off));

    __shared__ float redm[8], reds[8];
    if (lane == 0) redm[wave] = m;
    __syncthreads();
    m = redm[0];
#pragma unroll
    for (int w = 1; w < 8; ++w) m = fmaxf(m, redm[w]);

    v.x = expf(v.x - m); v.y = expf(v.y - m);
    v.z = expf(v.z - m); v.w = expf(v.w - m);
    float s = v.x + v.y + v.z + v.w;
#pragma unroll
    for (int off = 1; off < 64; off <<= 1)
        s += __shfl_xor(s, off);
    if (lane == 0) reds[wave] = s;
    __syncthreads();
    s = reds[0];
#pragma unroll
    for (int w = 1; w < 8; ++w) s += reds[w];

    const float inv = 1.0f / s;
    v *= inv;
    ((f4*)(out + (size_t)b * T_DIM))[tid] = v;
}

extern "C" void kernel_launch(void* const* d_in, const int* in_sizes, int n_in,
                              void* d_out, int out_size, void* d_ws, size_t ws_size,
                              hipStream_t stream) {
    const float* hidden = (const float*)d_in[0];  // [1,B,H]
    const float* enc    = (const float*)d_in[1];  // [T,B,H]
    const float* W      = (const float*)d_in[2];  // [H,H]
    // d_in[3] = b_attn: per-b constant under softmax -> cancels exactly.

    float* out    = (float*)d_out;                        // [B,1,T]
    float* q      = (float*)d_ws;                         // B*H  (256 KB)
    float* scores = (float*)d_ws + (size_t)B_DIM * H_DIM; // B*T  (512 KB)

    qproj_kernel  <<<dim3(H_DIM / 256, B_DIM / 4), 512, 0, stream>>>(hidden, W, q);
    scores_kernel <<<dim3(T_DIM / TC, B_DIM / 16), 512, 0, stream>>>(enc, q, scores);
    softmax_kernel<<<dim3(B_DIM),                  512, 0, stream>>>(scores, out);
}